// Round 4
// baseline (1409.585 us; speedup 1.0000x reference)
//
#include <hip/hip_runtime.h>
#include <hip/hip_bf16.h>
#include <stdint.h>

#define BB 16
#define NN 4096
#define NPOINT 1024
#define NSAMPLE 32

typedef unsigned int u32;
typedef unsigned long long u64;
typedef unsigned short u16;
typedef float f32x2 __attribute__((ext_vector_type(2)));

__device__ inline u16 f2bf(float x){ u32 u = __float_as_uint(x); u32 r = (u + 0x7fffu + ((u>>16)&1u)) >> 16; return (u16)r; }
__device__ inline float bf2f(u32 hbits){ return __uint_as_float(hbits<<16); }

// full-wave (64-lane) f32 max via DPP; result bits returned from lane 63.
__device__ inline int wave_max_bits(float v){
    int x = __float_as_int(v);
    int t;
    t = __builtin_amdgcn_update_dpp(0, x, 0x111, 0xf, 0xf, true);  // row_shr:1
    x = __float_as_int(fmaxf(__int_as_float(x), __int_as_float(t)));
    t = __builtin_amdgcn_update_dpp(0, x, 0x112, 0xf, 0xf, true);  // row_shr:2
    x = __float_as_int(fmaxf(__int_as_float(x), __int_as_float(t)));
    t = __builtin_amdgcn_update_dpp(0, x, 0x114, 0xf, 0xf, true);  // row_shr:4
    x = __float_as_int(fmaxf(__int_as_float(x), __int_as_float(t)));
    t = __builtin_amdgcn_update_dpp(0, x, 0x118, 0xf, 0xf, true);  // row_shr:8
    x = __float_as_int(fmaxf(__int_as_float(x), __int_as_float(t)));
    t = __builtin_amdgcn_update_dpp(0, x, 0x142, 0xf, 0xf, true);  // row_bcast:15
    x = __float_as_int(fmaxf(__int_as_float(x), __int_as_float(t)));
    t = __builtin_amdgcn_update_dpp(0, x, 0x143, 0xf, 0xf, true);  // row_bcast:31
    x = __float_as_int(fmaxf(__int_as_float(x), __int_as_float(t)));
    return __builtin_amdgcn_readlane(x, 63);
}

// ---------------- FPS: 4 waves, value-only packed tracking, coord-fused slots,
// ---------------- cents in LDS (no global store -> no vmcnt drain at barrier) ----------------
__global__ __launch_bounds__(256) void fps_kernel(const float* __restrict__ xyz, int* __restrict__ cents)
{
#pragma clang fp contract(off)
    __shared__ float lxyz[NN*3];
    __shared__ int lcents[NPOINT];
    __shared__ __align__(16) u32 s_wmb[2][4];
    __shared__ __align__(16) float4 s_cd[2][4];
    const int tid = threadIdx.x;
    const int b = blockIdx.x;
    const float* gx = xyz + (size_t)b*NN*3;
    for (int i = tid; i < NN*3; i += 256) lxyz[i] = gx[i];
    __syncthreads();
    // thread owns points p = tid*16 + j, j in [0,16): p = wid<<10 | lane<<4 | j (ascending)
    f32x2 px[8], py[8], pz[8], dist[8];
#pragma unroll
    for (int jj = 0; jj < 8; jj++){
        int p = tid*16 + jj*2;
        px[jj] = (f32x2){ lxyz[p*3+0], lxyz[(p+1)*3+0] };
        py[jj] = (f32x2){ lxyz[p*3+1], lxyz[(p+1)*3+1] };
        pz[jj] = (f32x2){ lxyz[p*3+2], lxyz[(p+1)*3+2] };
        dist[jj] = (f32x2){ 1e10f, 1e10f };
    }
    const int lane = tid & 63;
    const int wid = tid >> 6;
    int far = 0, par = 0;
    float cx = lxyz[0], cy = lxyz[1], cz = lxyz[2];
    for (int s = 0; s < NPOINT; s++){
        if (tid == 0) lcents[s] = far;
        f32x2 c2x = { cx, cx }, c2y = { cy, cy }, c2z = { cz, cz };
        f32x2 bm = { -1.0f, -1.0f };
#pragma unroll
        for (int jj = 0; jj < 8; jj++){
            f32x2 dx = px[jj] - c2x;
            f32x2 dy = py[jj] - c2y;
            f32x2 dz = pz[jj] - c2z;
            f32x2 d  = (dx*dx + dy*dy) + dz*dz;     // contract(off): exact _rn order
            f32x2 nd = __builtin_elementwise_min(dist[jj], d);
            dist[jj] = nd;
            bm = __builtin_elementwise_max(bm, nd);
        }
        float bv = fmaxf(bm.x, bm.y);
        int wmb = wave_max_bits(bv);
        float wmax = __int_as_float(wmb);
        // local first-j recovery: dist[] holds the final per-point values of this step
        u32 mj = 0;
#pragma unroll
        for (int jj = 0; jj < 8; jj++){
            if (dist[jj].x == wmax) mj |= (1u << (jj*2));
            if (dist[jj].y == wmax) mj |= (1u << (jj*2+1));
        }
        u64 mask = __ballot(mj != 0);
        int fl = __ffsll((long long)mask) - 1;             // lowest lane => lowest p
        u32 mjw = (u32)__builtin_amdgcn_readlane((int)mj, fl);
        int fj = __ffs(mjw) - 1;                           // lowest j
        int p = (wid << 10) + (fl << 4) + fj;
        // wave-uniform candidate coords (broadcast LDS read, pre-barrier)
        float qx = lxyz[p*3+0], qy = lxyz[p*3+1], qz = lxyz[p*3+2];
        if (lane == 0){
            s_wmb[par][wid] = (u32)wmb;
            s_cd[par][wid] = make_float4(qx, qy, qz, __int_as_float(p));
        }
        __syncthreads();
        uint4 keys = *(const uint4*)&s_wmb[par][0];
        float4 c0 = s_cd[par][0], c1 = s_cd[par][1], c2 = s_cd[par][2], c3 = s_cd[par][3];
        u32 bk = keys.x; float4 bc = c0;
        if (keys.y > bk){ bk = keys.y; bc = c1; }          // strict > keeps lowest wid => lowest p
        if (keys.z > bk){ bk = keys.z; bc = c2; }
        if (keys.w > bk){ bk = keys.w; bc = c3; }
        cx = bc.x; cy = bc.y; cz = bc.z; far = __float_as_int(bc.w);
        par ^= 1;
    }
    __syncthreads();
    for (int i = tid; i < NPOINT; i += 256) cents[b*NPOINT + i] = lcents[i];
}

// ---------------- gather new_xyz -> d_out[0:49152] and ws copy ----------------
__global__ __launch_bounds__(256) void gather_newxyz_kernel(const float* __restrict__ xyz, const int* __restrict__ cents,
                                                            float* __restrict__ out, float* __restrict__ nxyz)
{
    int i = blockIdx.x*256 + threadIdx.x;   // < 49152
    int b = i / 3072;
    int r = i - b*3072;
    int s = r / 3;
    int c = r - s*3;
    int idx = cents[b*NPOINT + s];
    float v = xyz[((size_t)b*NN + idx)*3 + c];
    out[i] = v;
    nxyz[i] = v;
}

// ---------------- ball query: one wave per centroid, early exit ----------------
__global__ __launch_bounds__(256) void ballquery_kernel(const float* __restrict__ xyz, const float* __restrict__ nxyz,
                                                        const int* __restrict__ cents, int* __restrict__ gidx)
{
    const int lane = threadIdx.x & 63;
    const int w = (blockIdx.x << 2) + (threadIdx.x >> 6);
    const int b = w >> 10;
    const float RAD2 = (float)(0.9*0.9);
    const float* c3 = nxyz + (size_t)w*3;
    float cx = c3[0], cy = c3[1], cz = c3[2];
    float sc = __fadd_rn(__fadd_rn(__fmul_rn(cx,cx), __fmul_rn(cy,cy)), __fmul_rn(cz,cz));
    const float* gx = xyz + (size_t)b*NN*3;
    int* gout = gidx + (size_t)w*NSAMPLE;
    int found = 0; int first = -1;
    for (int base = 0; base < NN; base += 64){
        int i = base + lane;
        float pxv = gx[i*3+0], pyv = gx[i*3+1], pzv = gx[i*3+2];
        float sp = __fadd_rn(__fadd_rn(__fmul_rn(pxv,pxv), __fmul_rn(pyv,pyv)), __fmul_rn(pzv,pzv));
        float dot = __fadd_rn(__fadd_rn(__fmul_rn(cx,pxv), __fmul_rn(cy,pyv)), __fmul_rn(cz,pzv));
        float d2 = __fsub_rn(__fadd_rn(sc, sp), __fmul_rn(2.0f, dot));
        float dd = __fsqrt_rn(fmaxf(d2, 0.0f));
        bool in = !(dd > RAD2);
        u64 m = __ballot(in);
        int cnt = __popcll(m);
        if (in){
            int slot = found + __popcll(m & ((1ull<<lane) - 1ull));
            if (slot < NSAMPLE) gout[slot] = i;
        }
        if (found == 0 && cnt > 0) first = base + (__ffsll(m) - 1);
        found += cnt;
        if (found >= NSAMPLE) break;
    }
    if (found < NSAMPLE){
        if (found == 0) first = cents[w];
        for (int slot = found + lane; slot < NSAMPLE; slot += 64) gout[slot] = first;
    }
}

// ---------------- conv1: 67->64, thread = 4 samples x 16 outputs, fused stats ----------------
__global__ __launch_bounds__(256) void conv1_kernel(const float* __restrict__ xyz, const float* __restrict__ points,
                                                    const float* __restrict__ nxyz, const int* __restrict__ gidx,
                                                    const float* __restrict__ w, const float* __restrict__ bias,
                                                    u32* __restrict__ xout, float* __restrict__ stats)
{
    __shared__ float wl[67*64];   // [c][o]
    __shared__ float bl[64], ls[8][64], lq[8][64];
    const int tid = threadIdx.x;
    for (int i = tid; i < 67*64; i += 256){ int o = i/67, c = i - o*67; wl[c*64+o] = w[i]; }
    if (tid < 64){
        bl[tid] = bias[tid];
#pragma unroll
        for (int r = 0; r < 8; r++){ ls[r][tid] = 0.f; lq[r][tid] = 0.f; }
    }
    __syncthreads();
    const int og = tid & 3;
    const int ob = og*16;
    const int q  = tid >> 2;
    const int rp = q & 7;
    const int m0 = blockIdx.x*256 + q*4;
    const int b = m0 >> 15;
    const int s = (m0 >> 5) & 1023;
    int g[4];
#pragma unroll
    for (int i = 0; i < 4; i++) g[i] = gidx[m0+i];
    const float* c3 = nxyz + ((size_t)b*NPOINT + s)*3;
    float cx = c3[0], cy = c3[1], cz = c3[2];
    float acc[4][16];
#pragma unroll
    for (int i = 0; i < 4; i++)
#pragma unroll
        for (int o = 0; o < 16; o++) acc[i][o] = bl[ob+o];
    float fx[4], fy[4], fz[4];
#pragma unroll
    for (int i = 0; i < 4; i++){
        const float* p3 = xyz + ((size_t)b*NN + g[i])*3;
        fx[i] = p3[0]-cx; fy[i] = p3[1]-cy; fz[i] = p3[2]-cz;
    }
#pragma unroll
    for (int c = 0; c < 3; c++){
        const float* f = (c == 0) ? fx : (c == 1) ? fy : fz;
        const float* wp = &wl[c*64 + ob];
#pragma unroll
        for (int o = 0; o < 16; o++)
#pragma unroll
            for (int i = 0; i < 4; i++) acc[i][o] = fmaf(wp[o], f[i], acc[i][o]);
    }
    const float4* pr[4];
#pragma unroll
    for (int i = 0; i < 4; i++) pr[i] = (const float4*)(points + ((size_t)b*NN + g[i])*64);
#pragma unroll 4
    for (int c4 = 0; c4 < 16; c4++){
        float4 f[4];
#pragma unroll
        for (int i = 0; i < 4; i++) f[i] = pr[i][c4];
        const int cb = 3 + c4*4;
#pragma unroll
        for (int k = 0; k < 4; k++){
            const float* wp = &wl[(cb+k)*64 + ob];
#pragma unroll
            for (int o = 0; o < 16; o++){
                float wk = wp[o];
#pragma unroll
                for (int i = 0; i < 4; i++){
                    const float* fp = (const float*)&f[i];
                    acc[i][o] = fmaf(wk, fp[k], acc[i][o]);
                }
            }
        }
    }
#pragma unroll
    for (int i = 0; i < 4; i++){
        u32 tmp[8];
#pragma unroll
        for (int oo = 0; oo < 8; oo++)
            tmp[oo] = (u32)f2bf(acc[i][2*oo]) | ((u32)f2bf(acc[i][2*oo+1]) << 16);
        uint4* orow = (uint4*)(xout + (size_t)(m0+i)*32 + og*8);
        orow[0] = ((uint4*)tmp)[0];
        orow[1] = ((uint4*)tmp)[1];
    }
#pragma unroll
    for (int o = 0; o < 16; o++){
        float sv = acc[0][o]+acc[1][o]+acc[2][o]+acc[3][o];
        float qv = acc[0][o]*acc[0][o]+acc[1][o]*acc[1][o]+acc[2][o]*acc[2][o]+acc[3][o]*acc[3][o];
        atomicAdd(&ls[rp][ob+o], sv);
        atomicAdd(&lq[rp][ob+o], qv);
    }
    __syncthreads();
    if (tid < 64){
        float sm = 0.f, sq = 0.f;
#pragma unroll
        for (int r = 0; r < 8; r++){ sm += ls[r][tid]; sq += lq[r][tid]; }
        float* st = stats + (blockIdx.x & 7)*256;
        atomicAdd(&st[tid], sm);
        atomicAdd(&st[128+tid], sq);
    }
}

// ---------------- conv2: 64->64, normalize+relu on load, fused stats ----------------
__global__ __launch_bounds__(256) void conv2_kernel(const u32* __restrict__ xin, const float* __restrict__ aff,
                                                    const float* __restrict__ w, const float* __restrict__ bias,
                                                    u32* __restrict__ xout, float* __restrict__ stats)
{
    __shared__ float wl[64*64];   // [c][o]
    __shared__ float al[64], blv[64], biasl[64], ls[8][64], lq[8][64];
    const int tid = threadIdx.x;
    for (int i = tid; i < 4096; i += 256){ int o = i >> 6, c = i & 63; wl[c*64+o] = w[i]; }
    if (tid < 64){
        al[tid]=aff[tid]; blv[tid]=aff[128+tid]; biasl[tid]=bias[tid];
#pragma unroll
        for (int r = 0; r < 8; r++){ ls[r][tid] = 0.f; lq[r][tid] = 0.f; }
    }
    __syncthreads();
    const int og = tid & 3;
    const int ob = og*16;
    const int q  = tid >> 2;
    const int rp = q & 7;
    const int m0 = blockIdx.x*256 + q*4;
    const uint4* r0 = (const uint4*)(xin + (size_t)m0*32);
    const uint4* r1 = r0 + 8;
    const uint4* r2 = r0 + 16;
    const uint4* r3 = r0 + 24;
    float acc[4][16];
#pragma unroll
    for (int i = 0; i < 4; i++)
#pragma unroll
        for (int o = 0; o < 16; o++) acc[i][o] = biasl[ob+o];
#pragma unroll 2
    for (int cu = 0; cu < 8; cu++){
        uint4 u0 = r0[cu], u1 = r1[cu], u2 = r2[cu], u3 = r3[cu];
        u32 wa[4][4] = {{u0.x,u0.y,u0.z,u0.w},{u1.x,u1.y,u1.z,u1.w},{u2.x,u2.y,u2.z,u2.w},{u3.x,u3.y,u3.z,u3.w}};
#pragma unroll
        for (int wd = 0; wd < 4; wd++){
            const int c = cu*8 + wd*2;
            float f0[4], f1[4];
#pragma unroll
            for (int i = 0; i < 4; i++){
                u32 uw = wa[i][wd];
                f0[i] = fmaxf(fmaf(al[c],   bf2f(uw & 0xffffu), blv[c]),   0.f);
                f1[i] = fmaxf(fmaf(al[c+1], bf2f(uw >> 16),     blv[c+1]), 0.f);
            }
            const float* w0p = &wl[c*64 + ob];
            const float* w1p = &wl[(c+1)*64 + ob];
#pragma unroll
            for (int o = 0; o < 16; o++){
                float w0 = w0p[o], w1 = w1p[o];
#pragma unroll
                for (int i = 0; i < 4; i++){
                    float a = acc[i][o];
                    a = fmaf(w0, f0[i], a);
                    acc[i][o] = fmaf(w1, f1[i], a);
                }
            }
        }
    }
#pragma unroll
    for (int i = 0; i < 4; i++){
        u32 tmp[8];
#pragma unroll
        for (int oo = 0; oo < 8; oo++)
            tmp[oo] = (u32)f2bf(acc[i][2*oo]) | ((u32)f2bf(acc[i][2*oo+1]) << 16);
        uint4* orow = (uint4*)(xout + (size_t)(m0+i)*32 + og*8);
        orow[0] = ((uint4*)tmp)[0];
        orow[1] = ((uint4*)tmp)[1];
    }
#pragma unroll
    for (int o = 0; o < 16; o++){
        float sv = acc[0][o]+acc[1][o]+acc[2][o]+acc[3][o];
        float qv = acc[0][o]*acc[0][o]+acc[1][o]*acc[1][o]+acc[2][o]*acc[2][o]+acc[3][o]*acc[3][o];
        atomicAdd(&ls[rp][ob+o], sv);
        atomicAdd(&lq[rp][ob+o], qv);
    }
    __syncthreads();
    if (tid < 64){
        float sm = 0.f, sq = 0.f;
#pragma unroll
        for (int r = 0; r < 8; r++){ sm += ls[r][tid]; sq += lq[r][tid]; }
        float* st = stats + (blockIdx.x & 7)*256;
        atomicAdd(&st[tid], sm);
        atomicAdd(&st[128+tid], sq);
    }
}

// ---------------- conv3: 64->128, fused stats + fused group max/min (no x3 write) ----------------
__global__ __launch_bounds__(256) void conv3_kernel(const u32* __restrict__ xin, const float* __restrict__ aff,
                                                    const float* __restrict__ w, const float* __restrict__ bias,
                                                    float* __restrict__ gmax, float* __restrict__ gmin,
                                                    float* __restrict__ stats)
{
    __shared__ float wl[64*128];  // [c][o]
    __shared__ float al[64], blv[64], biasl[128], ls[8][128], lq[8][128];
    const int tid = threadIdx.x;
    for (int i = tid; i < 8192; i += 256){ int o = i >> 6, c = i & 63; wl[c*128+o] = w[i]; }
    if (tid < 64){ al[tid]=aff[tid]; blv[tid]=aff[128+tid]; }
    if (tid < 128){
        biasl[tid]=bias[tid];
#pragma unroll
        for (int r = 0; r < 8; r++){ ls[r][tid] = 0.f; lq[r][tid] = 0.f; }
    }
    __syncthreads();
    const int og = tid & 7;          // 8 o-groups x 16 = 128 outputs
    const int ob = og*16;
    const int q  = tid >> 3;         // 32 quads -> 128 samples -> 4 groups per block
    const int rp = q & 7;
    const int m0 = blockIdx.x*128 + q*4;
    const uint4* r0 = (const uint4*)(xin + (size_t)m0*32);
    const uint4* r1 = r0 + 8;
    const uint4* r2 = r0 + 16;
    const uint4* r3 = r0 + 24;
    float acc[4][16];
#pragma unroll
    for (int i = 0; i < 4; i++)
#pragma unroll
        for (int o = 0; o < 16; o++) acc[i][o] = biasl[ob+o];
#pragma unroll 2
    for (int cu = 0; cu < 8; cu++){
        uint4 u0 = r0[cu], u1 = r1[cu], u2 = r2[cu], u3 = r3[cu];
        u32 wa[4][4] = {{u0.x,u0.y,u0.z,u0.w},{u1.x,u1.y,u1.z,u1.w},{u2.x,u2.y,u2.z,u2.w},{u3.x,u3.y,u3.z,u3.w}};
#pragma unroll
        for (int wd = 0; wd < 4; wd++){
            const int c = cu*8 + wd*2;
            float f0[4], f1[4];
#pragma unroll
            for (int i = 0; i < 4; i++){
                u32 uw = wa[i][wd];
                f0[i] = fmaxf(fmaf(al[c],   bf2f(uw & 0xffffu), blv[c]),   0.f);
                f1[i] = fmaxf(fmaf(al[c+1], bf2f(uw >> 16),     blv[c+1]), 0.f);
            }
            const float* w0p = &wl[c*128 + ob];
            const float* w1p = &wl[(c+1)*128 + ob];
#pragma unroll
            for (int o = 0; o < 16; o++){
                float w0 = w0p[o], w1 = w1p[o];
#pragma unroll
                for (int i = 0; i < 4; i++){
                    float a = acc[i][o];
                    a = fmaf(w0, f0[i], a);
                    acc[i][o] = fmaf(w1, f1[i], a);
                }
            }
        }
    }
    // stats (raw conv output incl. bias)
#pragma unroll
    for (int o = 0; o < 16; o++){
        float sv = acc[0][o]+acc[1][o]+acc[2][o]+acc[3][o];
        float qv = acc[0][o]*acc[0][o]+acc[1][o]*acc[1][o]+acc[2][o]*acc[2][o]+acc[3][o]*acc[3][o];
        atomicAdd(&ls[rp][ob+o], sv);
        atomicAdd(&lq[rp][ob+o], qv);
    }
    // group max/min: one group per wave; quads are lane-groups of 8 -> shfl_xor 8/16/32
    float mx[16], mn[16];
#pragma unroll
    for (int o = 0; o < 16; o++){
        float a = fmaxf(fmaxf(acc[0][o], acc[1][o]), fmaxf(acc[2][o], acc[3][o]));
        float n = fminf(fminf(acc[0][o], acc[1][o]), fminf(acc[2][o], acc[3][o]));
        mx[o] = a; mn[o] = n;
    }
#pragma unroll
    for (int off = 8; off <= 32; off <<= 1){
#pragma unroll
        for (int o = 0; o < 16; o++){
            mx[o] = fmaxf(mx[o], __shfl_xor(mx[o], off));
            mn[o] = fminf(mn[o], __shfl_xor(mn[o], off));
        }
    }
    if ((q & 7) == 0){
        const int gq = blockIdx.x*4 + (q >> 3);
        float* gm = gmax + (size_t)gq*128 + ob;
        float* gn = gmin + (size_t)gq*128 + ob;
#pragma unroll
        for (int o = 0; o < 16; o++){ gm[o] = mx[o]; gn[o] = mn[o]; }
    }
    __syncthreads();
    if (tid < 128){
        float sm = 0.f, sq = 0.f;
#pragma unroll
        for (int r = 0; r < 8; r++){ sm += ls[r][tid]; sq += lq[r][tid]; }
        float* st = stats + (blockIdx.x & 7)*256;
        atomicAdd(&st[tid], sm);
        atomicAdd(&st[128+tid], sq);
    }
}

// ---------------- finalize: stats (8 replicas) -> affine a,b ----------------
__global__ void finalize_kernel(const float* __restrict__ stats, const float* __restrict__ g,
                                const float* __restrict__ beta, float* __restrict__ aff, int C)
{
    int c = threadIdx.x;
    if (c < C){
        float sm = 0.f, sq = 0.f;
#pragma unroll
        for (int r = 0; r < 8; r++){ sm += stats[r*256+c]; sq += stats[r*256+128+c]; }
        const float invM = 1.0f / 524288.0f;
        float mu  = sm * invM;
        float var = fmaxf(sq * invM - mu*mu, 0.0f);
        float inv = 1.0f / sqrtf(var + 1e-5f);
        float a = g[c] * inv;
        aff[c] = a;
        aff[128+c] = beta[c] - mu*a;
    }
}

// ---------------- pool: BN3 affine + relu from group max/min ----------------
__global__ __launch_bounds__(256) void pool_kernel(const float* __restrict__ gmax, const float* __restrict__ gmin,
                                                   const float* __restrict__ aff, float* __restrict__ out)
{
    int idx = blockIdx.x*256 + threadIdx.x;   // < 2097152
    int o = idx & 127;
    float a = aff[o], bsh = aff[128+o];
    float v = (a >= 0.f) ? fmaf(a, gmax[idx], bsh) : fmaf(a, gmin[idx], bsh);
    out[(size_t)BB*NPOINT*3 + idx] = fmaxf(v, 0.f);
}

extern "C" void kernel_launch(void* const* d_in, const int* in_sizes, int n_in,
                              void* d_out, int out_size, void* d_ws, size_t ws_size,
                              hipStream_t stream)
{
    const float* xyz    = (const float*)d_in[0];
    const float* points = (const float*)d_in[1];
    const float* w0  = (const float*)d_in[2];
    const float* b0  = (const float*)d_in[3];
    const float* g0  = (const float*)d_in[4];
    const float* be0 = (const float*)d_in[5];
    const float* w1  = (const float*)d_in[6];
    const float* b1  = (const float*)d_in[7];
    const float* g1  = (const float*)d_in[8];
    const float* be1 = (const float*)d_in[9];
    const float* w2  = (const float*)d_in[10];
    const float* b2  = (const float*)d_in[11];
    const float* g2  = (const float*)d_in[12];
    const float* be2 = (const float*)d_in[13];
    float* out = (float*)d_out;
    char* ws = (char*)d_ws;

    int*   cents = (int*)(ws + 0);                 //  64 KiB
    float* nxyz  = (float*)(ws + 65536);           // 192 KiB
    int*   gidx  = (int*)(ws + 262144);            //   2 MiB -> ends 2359296
    float* stats = (float*)(ws + 2359296);         //  24 KiB (3 layers x 8 replicas x 256 f)
    float* aff   = (float*)(ws + 2383872);         //   3 KiB (3 layers x [a128|b128])
    u32*   x1buf = (u32*)(ws + 2386944);           //  64 MiB (conv1 out bf16)
    u32*   x2buf = (u32*)(ws + 69495808);          //  64 MiB (conv2 out bf16)
    float* gmax  = (float*)(ws + 136604672);       // 8.4 MiB
    float* gmin  = (float*)(ws + 144993280);       // 8.4 MiB

    hipMemsetAsync(stats, 0, 6144*sizeof(float), stream);
    fps_kernel<<<16, 256, 0, stream>>>(xyz, cents);
    gather_newxyz_kernel<<<192, 256, 0, stream>>>(xyz, cents, out, nxyz);
    ballquery_kernel<<<4096, 256, 0, stream>>>(xyz, nxyz, cents, gidx);
    conv1_kernel<<<2048, 256, 0, stream>>>(xyz, points, nxyz, gidx, w0, b0, x1buf, stats);
    finalize_kernel<<<1, 128, 0, stream>>>(stats, g0, be0, aff, 64);
    conv2_kernel<<<2048, 256, 0, stream>>>(x1buf, aff, w1, b1, x2buf, stats + 2048);
    finalize_kernel<<<1, 128, 0, stream>>>(stats + 2048, g1, be1, aff + 256, 64);
    conv3_kernel<<<4096, 256, 0, stream>>>(x2buf, aff + 256, w2, b2, gmax, gmin, stats + 4096);
    finalize_kernel<<<1, 128, 0, stream>>>(stats + 4096, g2, be2, aff + 512, 128);
    pool_kernel<<<8192, 256, 0, stream>>>(gmax, gmin, aff + 512, out);
}

// Round 5
// 900.191 us; speedup vs baseline: 1.5659x; 1.5659x over previous
//
#include <hip/hip_runtime.h>
#include <hip/hip_bf16.h>
#include <stdint.h>

#define BB 16
#define NN 4096
#define NPOINT 1024
#define NSAMPLE 32

typedef unsigned int u32;
typedef unsigned long long u64;
typedef unsigned short u16;
typedef float f32x2 __attribute__((ext_vector_type(2)));
using frag_ab = __attribute__((ext_vector_type(8))) short;   // 8 bf16 (4 VGPRs)
using frag_cd = __attribute__((ext_vector_type(4))) float;   // 4 fp32

__device__ inline u16 f2bf(float x){ u32 u = __float_as_uint(x); u32 r = (u + 0x7fffu + ((u>>16)&1u)) >> 16; return (u16)r; }
__device__ inline float bf2f(u32 hbits){ return __uint_as_float(hbits<<16); }
__device__ inline u64 umax64(u64 a, u64 b){ return a > b ? a : b; }

// full-wave (64-lane) f32 max via DPP; result bits returned from lane 63.
__device__ inline int wave_max_bits(float v){
    int x = __float_as_int(v);
    int t;
    t = __builtin_amdgcn_update_dpp(0, x, 0x111, 0xf, 0xf, true);  // row_shr:1
    x = __float_as_int(fmaxf(__int_as_float(x), __int_as_float(t)));
    t = __builtin_amdgcn_update_dpp(0, x, 0x112, 0xf, 0xf, true);  // row_shr:2
    x = __float_as_int(fmaxf(__int_as_float(x), __int_as_float(t)));
    t = __builtin_amdgcn_update_dpp(0, x, 0x114, 0xf, 0xf, true);  // row_shr:4
    x = __float_as_int(fmaxf(__int_as_float(x), __int_as_float(t)));
    t = __builtin_amdgcn_update_dpp(0, x, 0x118, 0xf, 0xf, true);  // row_shr:8
    x = __float_as_int(fmaxf(__int_as_float(x), __int_as_float(t)));
    t = __builtin_amdgcn_update_dpp(0, x, 0x142, 0xf, 0xf, true);  // row_bcast:15
    x = __float_as_int(fmaxf(__int_as_float(x), __int_as_float(t)));
    t = __builtin_amdgcn_update_dpp(0, x, 0x143, 0xf, 0xf, true);  // row_bcast:31
    x = __float_as_int(fmaxf(__int_as_float(x), __int_as_float(t)));
    return __builtin_amdgcn_readlane(x, 63);
}

// ---------------- FPS: R3 machinery (544us known-good) + cents in LDS ----------------
__global__ __launch_bounds__(256) void fps_kernel(const float* __restrict__ xyz, int* __restrict__ cents)
{
#pragma clang fp contract(off)
    __shared__ float lxyz[NN*3];
    __shared__ int lcents[NPOINT];
    __shared__ __align__(16) u64 s_red[2][4];
    const int tid = threadIdx.x;
    const int b = blockIdx.x;
    const float* gx = xyz + (size_t)b*NN*3;
    for (int i = tid; i < NN*3; i += 256) lxyz[i] = gx[i];
    __syncthreads();
    f32x2 px[8], py[8], pz[8], dist[8];
#pragma unroll
    for (int jj = 0; jj < 8; jj++){
        int p = tid*16 + jj*2;
        px[jj] = (f32x2){ lxyz[p*3+0], lxyz[(p+1)*3+0] };
        py[jj] = (f32x2){ lxyz[p*3+1], lxyz[(p+1)*3+1] };
        pz[jj] = (f32x2){ lxyz[p*3+2], lxyz[(p+1)*3+2] };
        dist[jj] = (f32x2){ 1e10f, 1e10f };
    }
    const int lane = tid & 63;
    const int wid = tid >> 6;
    int far = 0, par = 0;
    for (int s = 0; s < NPOINT; s++){
        if (tid == 0) lcents[s] = far;
        float cx = lxyz[far*3+0], cy = lxyz[far*3+1], cz = lxyz[far*3+2];
        f32x2 c2x = { cx, cx }, c2y = { cy, cy }, c2z = { cz, cz };
        float bv = -1.0f; int bj = 0;
#pragma unroll
        for (int jj = 0; jj < 8; jj++){
            f32x2 dx = px[jj] - c2x;
            f32x2 dy = py[jj] - c2y;
            f32x2 dz = pz[jj] - c2z;
            f32x2 d  = (dx*dx + dy*dy) + dz*dz;     // contract(off): exact _rn order
            f32x2 nd;
            nd.x = fminf(dist[jj].x, d.x);
            nd.y = fminf(dist[jj].y, d.y);
            dist[jj] = nd;
            if (nd.x > bv){ bv = nd.x; bj = jj*2; }       // ascending j => first-max kept
            if (nd.y > bv){ bv = nd.y; bj = jj*2+1; }
        }
        int wmb = wave_max_bits(bv);
        float wmax = __int_as_float(wmb);
        u64 mask = __ballot(bv == wmax);
        int fl = __ffsll((long long)mask) - 1;             // lowest lane => lowest p
        int fj = __builtin_amdgcn_readlane(bj, fl);
        int p = (wid << 10) + (fl << 4) + fj;
        if (lane == 0) s_red[par][wid] = ((u64)(u32)wmb << 32) | (u32)(4095 - p);
        __syncthreads();
        u64 m0 = umax64(s_red[par][0], s_red[par][1]);
        u64 m1 = umax64(s_red[par][2], s_red[par][3]);
        u64 m  = umax64(m0, m1);
        far = 4095 - (int)(m & 0xFFFu);
        par ^= 1;
    }
    __syncthreads();
    for (int i = tid; i < NPOINT; i += 256) cents[b*NPOINT + i] = lcents[i];
}

// ---------------- gather new_xyz -> d_out[0:49152] and ws copy ----------------
__global__ __launch_bounds__(256) void gather_newxyz_kernel(const float* __restrict__ xyz, const int* __restrict__ cents,
                                                            float* __restrict__ out, float* __restrict__ nxyz)
{
    int i = blockIdx.x*256 + threadIdx.x;   // < 49152
    int b = i / 3072;
    int r = i - b*3072;
    int s = r / 3;
    int c = r - s*3;
    int idx = cents[b*NPOINT + s];
    float v = xyz[((size_t)b*NN + idx)*3 + c];
    out[i] = v;
    nxyz[i] = v;
}

// ---------------- ball query: one wave per centroid, early exit ----------------
__global__ __launch_bounds__(256) void ballquery_kernel(const float* __restrict__ xyz, const float* __restrict__ nxyz,
                                                        const int* __restrict__ cents, int* __restrict__ gidx)
{
    const int lane = threadIdx.x & 63;
    const int w = (blockIdx.x << 2) + (threadIdx.x >> 6);
    const int b = w >> 10;
    const float RAD2 = (float)(0.9*0.9);
    const float* c3 = nxyz + (size_t)w*3;
    float cx = c3[0], cy = c3[1], cz = c3[2];
    float sc = __fadd_rn(__fadd_rn(__fmul_rn(cx,cx), __fmul_rn(cy,cy)), __fmul_rn(cz,cz));
    const float* gx = xyz + (size_t)b*NN*3;
    int* gout = gidx + (size_t)w*NSAMPLE;
    int found = 0; int first = -1;
    for (int base = 0; base < NN; base += 64){
        int i = base + lane;
        float pxv = gx[i*3+0], pyv = gx[i*3+1], pzv = gx[i*3+2];
        float sp = __fadd_rn(__fadd_rn(__fmul_rn(pxv,pxv), __fmul_rn(pyv,pyv)), __fmul_rn(pzv,pzv));
        float dot = __fadd_rn(__fadd_rn(__fmul_rn(cx,pxv), __fmul_rn(cy,pyv)), __fmul_rn(cz,pzv));
        float d2 = __fsub_rn(__fadd_rn(sc, sp), __fmul_rn(2.0f, dot));
        float dd = __fsqrt_rn(fmaxf(d2, 0.0f));
        bool in = !(dd > RAD2);
        u64 m = __ballot(in);
        int cnt = __popcll(m);
        if (in){
            int slot = found + __popcll(m & ((1ull<<lane) - 1ull));
            if (slot < NSAMPLE) gout[slot] = i;
        }
        if (found == 0 && cnt > 0) first = base + (__ffsll(m) - 1);
        found += cnt;
        if (found >= NSAMPLE) break;
    }
    if (found < NSAMPLE){
        if (found == 0) first = cents[w];
        for (int slot = found + lane; slot < NSAMPLE; slot += 64) gout[slot] = first;
    }
}

// ---------------- conv1: 67->64, thread = 4 samples x 16 outputs, fused stats ----------------
__global__ __launch_bounds__(256) void conv1_kernel(const float* __restrict__ xyz, const float* __restrict__ points,
                                                    const float* __restrict__ nxyz, const int* __restrict__ gidx,
                                                    const float* __restrict__ w, const float* __restrict__ bias,
                                                    u32* __restrict__ xout, float* __restrict__ stats)
{
    __shared__ float wl[67*64];   // [c][o]
    __shared__ float bl[64], ls[8][64], lq[8][64];
    const int tid = threadIdx.x;
    for (int i = tid; i < 67*64; i += 256){ int o = i/67, c = i - o*67; wl[c*64+o] = w[i]; }
    if (tid < 64){
        bl[tid] = bias[tid];
#pragma unroll
        for (int r = 0; r < 8; r++){ ls[r][tid] = 0.f; lq[r][tid] = 0.f; }
    }
    __syncthreads();
    const int og = tid & 3;
    const int ob = og*16;
    const int q  = tid >> 2;
    const int rp = q & 7;
    const int m0 = blockIdx.x*256 + q*4;
    const int b = m0 >> 15;
    const int s = (m0 >> 5) & 1023;
    int g[4];
#pragma unroll
    for (int i = 0; i < 4; i++) g[i] = gidx[m0+i];
    const float* c3 = nxyz + ((size_t)b*NPOINT + s)*3;
    float cx = c3[0], cy = c3[1], cz = c3[2];
    float acc[4][16];
#pragma unroll
    for (int i = 0; i < 4; i++)
#pragma unroll
        for (int o = 0; o < 16; o++) acc[i][o] = bl[ob+o];
    float fx[4], fy[4], fz[4];
#pragma unroll
    for (int i = 0; i < 4; i++){
        const float* p3 = xyz + ((size_t)b*NN + g[i])*3;
        fx[i] = p3[0]-cx; fy[i] = p3[1]-cy; fz[i] = p3[2]-cz;
    }
#pragma unroll
    for (int c = 0; c < 3; c++){
        const float* f = (c == 0) ? fx : (c == 1) ? fy : fz;
        const float* wp = &wl[c*64 + ob];
#pragma unroll
        for (int o = 0; o < 16; o++)
#pragma unroll
            for (int i = 0; i < 4; i++) acc[i][o] = fmaf(wp[o], f[i], acc[i][o]);
    }
    const float4* pr[4];
#pragma unroll
    for (int i = 0; i < 4; i++) pr[i] = (const float4*)(points + ((size_t)b*NN + g[i])*64);
#pragma unroll 4
    for (int c4 = 0; c4 < 16; c4++){
        float4 f[4];
#pragma unroll
        for (int i = 0; i < 4; i++) f[i] = pr[i][c4];
        const int cb = 3 + c4*4;
#pragma unroll
        for (int k = 0; k < 4; k++){
            const float* wp = &wl[(cb+k)*64 + ob];
#pragma unroll
            for (int o = 0; o < 16; o++){
                float wk = wp[o];
#pragma unroll
                for (int i = 0; i < 4; i++){
                    const float* fp = (const float*)&f[i];
                    acc[i][o] = fmaf(wk, fp[k], acc[i][o]);
                }
            }
        }
    }
#pragma unroll
    for (int i = 0; i < 4; i++){
        u32 tmp[8];
#pragma unroll
        for (int oo = 0; oo < 8; oo++)
            tmp[oo] = (u32)f2bf(acc[i][2*oo]) | ((u32)f2bf(acc[i][2*oo+1]) << 16);
        uint4* orow = (uint4*)(xout + (size_t)(m0+i)*32 + og*8);
        orow[0] = ((uint4*)tmp)[0];
        orow[1] = ((uint4*)tmp)[1];
    }
#pragma unroll
    for (int o = 0; o < 16; o++){
        float sv = acc[0][o]+acc[1][o]+acc[2][o]+acc[3][o];
        float qv = acc[0][o]*acc[0][o]+acc[1][o]*acc[1][o]+acc[2][o]*acc[2][o]+acc[3][o]*acc[3][o];
        atomicAdd(&ls[rp][ob+o], sv);
        atomicAdd(&lq[rp][ob+o], qv);
    }
    __syncthreads();
    if (tid < 64){
        float sm = 0.f, sq = 0.f;
#pragma unroll
        for (int r = 0; r < 8; r++){ sm += ls[r][tid]; sq += lq[r][tid]; }
        float* st = stats + (blockIdx.x & 7)*256;
        atomicAdd(&st[tid], sm);
        atomicAdd(&st[128+tid], sq);
    }
}

// ---- unpack 8 packed-bf16, apply affine+relu, emit bf16 frag half ----
__device__ inline void unpack_affine_relu(uint4 u, const float* ak, const float* bk, short* dst){
    const u32* uu = (const u32*)&u;
#pragma unroll
    for (int q = 0; q < 4; q++){
        u32 v = uu[q];
        float x0 = bf2f(v & 0xffffu);
        float x1 = bf2f(v >> 16);
        float f0 = fmaxf(fmaf(ak[2*q],   x0, bk[2*q]),   0.f);
        float f1 = fmaxf(fmaf(ak[2*q+1], x1, bk[2*q+1]), 0.f);
        dst[2*q]   = (short)f2bf(f0);
        dst[2*q+1] = (short)f2bf(f1);
    }
}

// ---------------- conv2 (MFMA): 64->64, BN1+relu on load, fused stats ----------------
// grid 512 blocks x 256; wave handles 16 m-tiles of 16 rows.
__global__ __launch_bounds__(256) void conv2_kernel(const u32* __restrict__ xin, const float* __restrict__ aff,
                                                    const float* __restrict__ w, const float* __restrict__ bias,
                                                    u32* __restrict__ xout, float* __restrict__ stats)
{
    const int tid = threadIdx.x;
    const int lane = tid & 63;
    const int wid = tid >> 6;
    const int quad = lane >> 4;
    const int col = lane & 15;
    // B-frags: Bf[nt][kh][j] = W[nt*16+col][kh*32 + quad*8 + j]
    frag_ab Bf[4][2];
#pragma unroll
    for (int nt = 0; nt < 4; nt++)
#pragma unroll
        for (int kh = 0; kh < 2; kh++){
            const float* wr = w + (nt*16 + col)*64 + kh*32 + quad*8;
#pragma unroll
            for (int j = 0; j < 8; j++) Bf[nt][kh][j] = (short)f2bf(wr[j]);
        }
    // per-lane affine for its k-slice
    float ak[2][8], bk[2][8];
#pragma unroll
    for (int kh = 0; kh < 2; kh++)
#pragma unroll
        for (int j = 0; j < 8; j++){
            int k = kh*32 + quad*8 + j;
            ak[kh][j] = aff[k]; bk[kh][j] = aff[128+k];
        }
    float biasl[4];
#pragma unroll
    for (int nt = 0; nt < 4; nt++) biasl[nt] = bias[nt*16 + col];
    float ssum[4] = {0,0,0,0}, ssq[4] = {0,0,0,0};
    u16* xo = (u16*)xout;
    const int tile0 = blockIdx.x*64 + wid*16;
    for (int t = 0; t < 16; t++){
        const size_t m0 = (size_t)(tile0 + t) * 16;
        const u32* arow = xin + (m0 + col)*32;
        uint4 u0 = *(const uint4*)(arow + quad*4);
        uint4 u1 = *(const uint4*)(arow + 16 + quad*4);
        frag_ab Af0, Af1;
        unpack_affine_relu(u0, ak[0], bk[0], (short*)&Af0);
        unpack_affine_relu(u1, ak[1], bk[1], (short*)&Af1);
        frag_cd acc[4];
#pragma unroll
        for (int nt = 0; nt < 4; nt++){
            acc[nt] = (frag_cd){biasl[nt], biasl[nt], biasl[nt], biasl[nt]};
            acc[nt] = __builtin_amdgcn_mfma_f32_16x16x32_bf16(Af0, Bf[nt][0], acc[nt], 0, 0, 0);
            acc[nt] = __builtin_amdgcn_mfma_f32_16x16x32_bf16(Af1, Bf[nt][1], acc[nt], 0, 0, 0);
        }
#pragma unroll
        for (int nt = 0; nt < 4; nt++){
#pragma unroll
            for (int r = 0; r < 4; r++){
                float v = acc[nt][r];
                xo[(m0 + quad*4 + r)*64 + nt*16 + col] = f2bf(v);
                ssum[nt] += v;
                ssq[nt] = fmaf(v, v, ssq[nt]);
            }
        }
    }
    // cross-quad reduce (lanes l, l^16, l^32, l^48 share col)
#pragma unroll
    for (int nt = 0; nt < 4; nt++){
        ssum[nt] += __shfl_xor(ssum[nt], 16); ssq[nt] += __shfl_xor(ssq[nt], 16);
        ssum[nt] += __shfl_xor(ssum[nt], 32); ssq[nt] += __shfl_xor(ssq[nt], 32);
    }
    if (quad == 0){
        float* st = stats + (blockIdx.x & 7)*256;
#pragma unroll
        for (int nt = 0; nt < 4; nt++){
            atomicAdd(&st[nt*16 + col], ssum[nt]);
            atomicAdd(&st[128 + nt*16 + col], ssq[nt]);
        }
    }
}

// ---------------- conv3 (MFMA): 64->128, BN2+relu on load, fused stats + group max/min ----------------
// grid 1024 blocks x 256; wave handles 8 consecutive m-tiles (= 4 groups of 32 rows).
__global__ __launch_bounds__(256) void conv3_kernel(const u32* __restrict__ xin, const float* __restrict__ aff,
                                                    const float* __restrict__ w, const float* __restrict__ bias,
                                                    float* __restrict__ gmax, float* __restrict__ gmin,
                                                    float* __restrict__ stats)
{
    const int tid = threadIdx.x;
    const int lane = tid & 63;
    const int wid = tid >> 6;
    const int quad = lane >> 4;
    const int col = lane & 15;
    frag_ab Bf[8][2];
#pragma unroll
    for (int nt = 0; nt < 8; nt++)
#pragma unroll
        for (int kh = 0; kh < 2; kh++){
            const float* wr = w + (nt*16 + col)*64 + kh*32 + quad*8;
#pragma unroll
            for (int j = 0; j < 8; j++) Bf[nt][kh][j] = (short)f2bf(wr[j]);
        }
    float ak[2][8], bk[2][8];
#pragma unroll
    for (int kh = 0; kh < 2; kh++)
#pragma unroll
        for (int j = 0; j < 8; j++){
            int k = kh*32 + quad*8 + j;
            ak[kh][j] = aff[k]; bk[kh][j] = aff[128+k];
        }
    float biasl[8];
#pragma unroll
    for (int nt = 0; nt < 8; nt++) biasl[nt] = bias[nt*16 + col];
    float ssum[8], ssq[8], mx[8], mn[8];
#pragma unroll
    for (int nt = 0; nt < 8; nt++){ ssum[nt] = 0.f; ssq[nt] = 0.f; }
    const int tile0 = blockIdx.x*32 + wid*8;
#pragma unroll 2
    for (int t = 0; t < 8; t++){
        const size_t m0 = (size_t)(tile0 + t) * 16;
        const u32* arow = xin + (m0 + col)*32;
        uint4 u0 = *(const uint4*)(arow + quad*4);
        uint4 u1 = *(const uint4*)(arow + 16 + quad*4);
        frag_ab Af0, Af1;
        unpack_affine_relu(u0, ak[0], bk[0], (short*)&Af0);
        unpack_affine_relu(u1, ak[1], bk[1], (short*)&Af1);
        frag_cd acc[8];
#pragma unroll
        for (int nt = 0; nt < 8; nt++){
            acc[nt] = (frag_cd){biasl[nt], biasl[nt], biasl[nt], biasl[nt]};
            acc[nt] = __builtin_amdgcn_mfma_f32_16x16x32_bf16(Af0, Bf[nt][0], acc[nt], 0, 0, 0);
            acc[nt] = __builtin_amdgcn_mfma_f32_16x16x32_bf16(Af1, Bf[nt][1], acc[nt], 0, 0, 0);
        }
#pragma unroll
        for (int nt = 0; nt < 8; nt++){
            float a0 = fmaxf(fmaxf(acc[nt][0], acc[nt][1]), fmaxf(acc[nt][2], acc[nt][3]));
            float n0 = fminf(fminf(acc[nt][0], acc[nt][1]), fminf(acc[nt][2], acc[nt][3]));
            if ((t & 1) == 0){ mx[nt] = a0; mn[nt] = n0; }
            else { mx[nt] = fmaxf(mx[nt], a0); mn[nt] = fminf(mn[nt], n0); }
#pragma unroll
            for (int r = 0; r < 4; r++){
                float v = acc[nt][r];
                ssum[nt] += v;
                ssq[nt] = fmaf(v, v, ssq[nt]);
            }
        }
        if (t & 1){
            // group of 32 rows complete: cross-quad max/min, quad0 writes
#pragma unroll
            for (int nt = 0; nt < 8; nt++){
                mx[nt] = fmaxf(mx[nt], __shfl_xor(mx[nt], 16));
                mn[nt] = fminf(mn[nt], __shfl_xor(mn[nt], 16));
                mx[nt] = fmaxf(mx[nt], __shfl_xor(mx[nt], 32));
                mn[nt] = fminf(mn[nt], __shfl_xor(mn[nt], 32));
            }
            if (quad == 0){
                const int g = (tile0 + t - 1) >> 1;
#pragma unroll
                for (int nt = 0; nt < 8; nt++){
                    gmax[(size_t)g*128 + nt*16 + col] = mx[nt];
                    gmin[(size_t)g*128 + nt*16 + col] = mn[nt];
                }
            }
        }
    }
#pragma unroll
    for (int nt = 0; nt < 8; nt++){
        ssum[nt] += __shfl_xor(ssum[nt], 16); ssq[nt] += __shfl_xor(ssq[nt], 16);
        ssum[nt] += __shfl_xor(ssum[nt], 32); ssq[nt] += __shfl_xor(ssq[nt], 32);
    }
    if (quad == 0){
        float* st = stats + (blockIdx.x & 7)*256;
#pragma unroll
        for (int nt = 0; nt < 8; nt++){
            atomicAdd(&st[nt*16 + col], ssum[nt]);
            atomicAdd(&st[128 + nt*16 + col], ssq[nt]);
        }
    }
}

// ---------------- finalize: stats (8 replicas) -> affine a,b ----------------
__global__ void finalize_kernel(const float* __restrict__ stats, const float* __restrict__ g,
                                const float* __restrict__ beta, float* __restrict__ aff, int C)
{
    int c = threadIdx.x;
    if (c < C){
        float sm = 0.f, sq = 0.f;
#pragma unroll
        for (int r = 0; r < 8; r++){ sm += stats[r*256+c]; sq += stats[r*256+128+c]; }
        const float invM = 1.0f / 524288.0f;
        float mu  = sm * invM;
        float var = fmaxf(sq * invM - mu*mu, 0.0f);
        float inv = 1.0f / sqrtf(var + 1e-5f);
        float a = g[c] * inv;
        aff[c] = a;
        aff[128+c] = beta[c] - mu*a;
    }
}

// ---------------- pool: BN3 affine + relu from group max/min ----------------
__global__ __launch_bounds__(256) void pool_kernel(const float* __restrict__ gmax, const float* __restrict__ gmin,
                                                   const float* __restrict__ aff, float* __restrict__ out)
{
    int idx = blockIdx.x*256 + threadIdx.x;   // < 2097152
    int o = idx & 127;
    float a = aff[o], bsh = aff[128+o];
    float v = (a >= 0.f) ? fmaf(a, gmax[idx], bsh) : fmaf(a, gmin[idx], bsh);
    out[(size_t)BB*NPOINT*3 + idx] = fmaxf(v, 0.f);
}

extern "C" void kernel_launch(void* const* d_in, const int* in_sizes, int n_in,
                              void* d_out, int out_size, void* d_ws, size_t ws_size,
                              hipStream_t stream)
{
    const float* xyz    = (const float*)d_in[0];
    const float* points = (const float*)d_in[1];
    const float* w0  = (const float*)d_in[2];
    const float* b0  = (const float*)d_in[3];
    const float* g0  = (const float*)d_in[4];
    const float* be0 = (const float*)d_in[5];
    const float* w1  = (const float*)d_in[6];
    const float* b1  = (const float*)d_in[7];
    const float* g1  = (const float*)d_in[8];
    const float* be1 = (const float*)d_in[9];
    const float* w2  = (const float*)d_in[10];
    const float* b2  = (const float*)d_in[11];
    const float* g2  = (const float*)d_in[12];
    const float* be2 = (const float*)d_in[13];
    float* out = (float*)d_out;
    char* ws = (char*)d_ws;

    int*   cents = (int*)(ws + 0);                 //  64 KiB
    float* nxyz  = (float*)(ws + 65536);           // 192 KiB
    int*   gidx  = (int*)(ws + 262144);            //   2 MiB -> ends 2359296
    float* stats = (float*)(ws + 2359296);         //  24 KiB (3 layers x 8 replicas x 256 f)
    float* aff   = (float*)(ws + 2383872);         //   3 KiB (3 layers x [a128|b128])
    u32*   x1buf = (u32*)(ws + 2386944);           //  64 MiB (conv1 out bf16)
    u32*   x2buf = (u32*)(ws + 69495808);          //  64 MiB (conv2 out bf16)
    float* gmax  = (float*)(ws + 136604672);       // 8.4 MiB
    float* gmin  = (float*)(ws + 144993280);       // 8.4 MiB

    hipMemsetAsync(stats, 0, 6144*sizeof(float), stream);
    fps_kernel<<<16, 256, 0, stream>>>(xyz, cents);
    gather_newxyz_kernel<<<192, 256, 0, stream>>>(xyz, cents, out, nxyz);
    ballquery_kernel<<<4096, 256, 0, stream>>>(xyz, nxyz, cents, gidx);
    conv1_kernel<<<2048, 256, 0, stream>>>(xyz, points, nxyz, gidx, w0, b0, x1buf, stats);
    finalize_kernel<<<1, 128, 0, stream>>>(stats, g0, be0, aff, 64);
    conv2_kernel<<<512, 256, 0, stream>>>(x1buf, aff, w1, b1, x2buf, stats + 2048);
    finalize_kernel<<<1, 128, 0, stream>>>(stats + 2048, g1, be1, aff + 256, 64);
    conv3_kernel<<<1024, 256, 0, stream>>>(x2buf, aff + 256, w2, b2, gmax, gmin, stats + 4096);
    finalize_kernel<<<1, 128, 0, stream>>>(stats + 4096, g2, be2, aff + 512, 128);
    pool_kernel<<<8192, 256, 0, stream>>>(gmax, gmin, aff + 512, out);
}

// Round 6
// 803.549 us; speedup vs baseline: 1.7542x; 1.1203x over previous
//
#include <hip/hip_runtime.h>
#include <hip/hip_bf16.h>
#include <stdint.h>

#define BB 16
#define NN 4096
#define NPOINT 1024
#define NSAMPLE 32

typedef unsigned int u32;
typedef unsigned long long u64;
typedef unsigned short u16;
typedef float f32x2 __attribute__((ext_vector_type(2)));
using frag_ab = __attribute__((ext_vector_type(8))) short;   // 8 bf16 (4 VGPRs)
using frag_cd = __attribute__((ext_vector_type(4))) float;   // 4 fp32

__device__ inline u16 f2bf(float x){ u32 u = __float_as_uint(x); u32 r = (u + 0x7fffu + ((u>>16)&1u)) >> 16; return (u16)r; }
__device__ inline float bf2f(u32 hbits){ return __uint_as_float(hbits<<16); }
__device__ inline u64 umax64(u64 a, u64 b){ return a > b ? a : b; }

// full-wave (64-lane) f32 max via DPP; result bits returned from lane 63.
__device__ inline int wave_max_bits(float v){
    int x = __float_as_int(v);
    int t;
    t = __builtin_amdgcn_update_dpp(0, x, 0x111, 0xf, 0xf, true);  // row_shr:1
    x = __float_as_int(fmaxf(__int_as_float(x), __int_as_float(t)));
    t = __builtin_amdgcn_update_dpp(0, x, 0x112, 0xf, 0xf, true);  // row_shr:2
    x = __float_as_int(fmaxf(__int_as_float(x), __int_as_float(t)));
    t = __builtin_amdgcn_update_dpp(0, x, 0x114, 0xf, 0xf, true);  // row_shr:4
    x = __float_as_int(fmaxf(__int_as_float(x), __int_as_float(t)));
    t = __builtin_amdgcn_update_dpp(0, x, 0x118, 0xf, 0xf, true);  // row_shr:8
    x = __float_as_int(fmaxf(__int_as_float(x), __int_as_float(t)));
    t = __builtin_amdgcn_update_dpp(0, x, 0x142, 0xf, 0xf, true);  // row_bcast:15
    x = __float_as_int(fmaxf(__int_as_float(x), __int_as_float(t)));
    t = __builtin_amdgcn_update_dpp(0, x, 0x143, 0xf, 0xf, true);  // row_bcast:31
    x = __float_as_int(fmaxf(__int_as_float(x), __int_as_float(t)));
    return __builtin_amdgcn_readlane(x, 63);
}

// ---------------- FPS: R3 base (global cents store) + pk-group value tracking ----------------
__global__ __launch_bounds__(256) void fps_kernel(const float* __restrict__ xyz, int* __restrict__ cents)
{
#pragma clang fp contract(off)
    __shared__ float lxyz[NN*3];
    __shared__ __align__(16) u64 s_red[2][4];
    const int tid = threadIdx.x;
    const int b = blockIdx.x;
    const float* gx = xyz + (size_t)b*NN*3;
    for (int i = tid; i < NN*3; i += 256) lxyz[i] = gx[i];
    __syncthreads();
    f32x2 px[8], py[8], pz[8], dist[8];
#pragma unroll
    for (int jj = 0; jj < 8; jj++){
        int p = tid*16 + jj*2;
        px[jj] = (f32x2){ lxyz[p*3+0], lxyz[(p+1)*3+0] };
        py[jj] = (f32x2){ lxyz[p*3+1], lxyz[(p+1)*3+1] };
        pz[jj] = (f32x2){ lxyz[p*3+2], lxyz[(p+1)*3+2] };
        dist[jj] = (f32x2){ 1e10f, 1e10f };
    }
    const int lane = tid & 63;
    const int wid = tid >> 6;
    int far = 0, par = 0;
    for (int s = 0; s < NPOINT; s++){
        if (tid == 0) cents[b*NPOINT + s] = far;
        float cx = lxyz[far*3+0], cy = lxyz[far*3+1], cz = lxyz[far*3+2];
        f32x2 c2x = { cx, cx }, c2y = { cy, cy }, c2z = { cz, cz };
        f32x2 bm0 = { -1.f, -1.f }, bm1 = { -1.f, -1.f };
#pragma unroll
        for (int jj = 0; jj < 8; jj++){
            f32x2 dx = px[jj] - c2x;
            f32x2 dy = py[jj] - c2y;
            f32x2 dz = pz[jj] - c2z;
            f32x2 d  = (dx*dx + dy*dy) + dz*dz;     // contract(off): exact _rn order
            f32x2 nd = __builtin_elementwise_min(dist[jj], d);
            dist[jj] = nd;
            if (jj < 4) bm0 = __builtin_elementwise_max(bm0, nd);
            else        bm1 = __builtin_elementwise_max(bm1, nd);
        }
        f32x2 bmA = __builtin_elementwise_max(bm0, bm1);
        float bv = fmaxf(bmA.x, bmA.y);
        int wmb = wave_max_bits(bv);
        float wmax = __int_as_float(wmb);
        u64 mask = __ballot(bv == wmax);
        int fl = __ffsll((long long)mask) - 1;             // lowest lane => lowest p
        // per-lane first-j recovery: pick group (0 preferred), scan its 4 pairs
        float g0m = fmaxf(bm0.x, bm0.y);
        int gsel = (g0m == wmax) ? 0 : 1;
        u32 mbits = 0;
#pragma unroll
        for (int u = 0; u < 4; u++){
            f32x2 dd = gsel ? dist[4+u] : dist[u];
            if (dd.x == wmax) mbits |= (1u << (2*u));
            if (dd.y == wmax) mbits |= (1u << (2*u+1));
        }
        int fj = (gsel << 3) + (__ffs(mbits) - 1);
        int fjw = __builtin_amdgcn_readlane(fj, fl);
        int p = (wid << 10) + (fl << 4) + fjw;
        if (lane == 0) s_red[par][wid] = ((u64)(u32)wmb << 32) | (u32)(4095 - p);
        __syncthreads();
        uint4 k01 = *(const uint4*)&s_red[par][0];
        uint4 k23 = *(const uint4*)&s_red[par][2];
        u64 r0 = ((u64)k01.y << 32) | k01.x;
        u64 r1 = ((u64)k01.w << 32) | k01.z;
        u64 r2 = ((u64)k23.y << 32) | k23.x;
        u64 r3 = ((u64)k23.w << 32) | k23.z;
        u64 m  = umax64(umax64(r0, r1), umax64(r2, r3));
        far = 4095 - (int)(m & 0xFFFu);
        par ^= 1;
    }
}

// ---------------- gather new_xyz -> d_out[0:49152] and ws copy ----------------
__global__ __launch_bounds__(256) void gather_newxyz_kernel(const float* __restrict__ xyz, const int* __restrict__ cents,
                                                            float* __restrict__ out, float* __restrict__ nxyz)
{
    int i = blockIdx.x*256 + threadIdx.x;   // < 49152
    int b = i / 3072;
    int r = i - b*3072;
    int s = r / 3;
    int c = r - s*3;
    int idx = cents[b*NPOINT + s];
    float v = xyz[((size_t)b*NN + idx)*3 + c];
    out[i] = v;
    nxyz[i] = v;
}

// ---------------- points -> packed bf16 ----------------
__global__ __launch_bounds__(256) void pack_points_kernel(const float* __restrict__ points, u32* __restrict__ pbf)
{
    int i = blockIdx.x*256 + threadIdx.x;   // < 2097152
    float f0 = points[2*i], f1 = points[2*i+1];
    pbf[i] = (u32)f2bf(f0) | ((u32)f2bf(f1) << 16);
}

// ---------------- ball query: one wave per centroid, early exit ----------------
__global__ __launch_bounds__(256) void ballquery_kernel(const float* __restrict__ xyz, const float* __restrict__ nxyz,
                                                        const int* __restrict__ cents, int* __restrict__ gidx)
{
    const int lane = threadIdx.x & 63;
    const int w = (blockIdx.x << 2) + (threadIdx.x >> 6);
    const int b = w >> 10;
    const float RAD2 = (float)(0.9*0.9);
    const float* c3 = nxyz + (size_t)w*3;
    float cx = c3[0], cy = c3[1], cz = c3[2];
    float sc = __fadd_rn(__fadd_rn(__fmul_rn(cx,cx), __fmul_rn(cy,cy)), __fmul_rn(cz,cz));
    const float* gx = xyz + (size_t)b*NN*3;
    int* gout = gidx + (size_t)w*NSAMPLE;
    int found = 0; int first = -1;
    for (int base = 0; base < NN; base += 64){
        int i = base + lane;
        float pxv = gx[i*3+0], pyv = gx[i*3+1], pzv = gx[i*3+2];
        float sp = __fadd_rn(__fadd_rn(__fmul_rn(pxv,pxv), __fmul_rn(pyv,pyv)), __fmul_rn(pzv,pzv));
        float dot = __fadd_rn(__fadd_rn(__fmul_rn(cx,pxv), __fmul_rn(cy,pyv)), __fmul_rn(cz,pzv));
        float d2 = __fsub_rn(__fadd_rn(sc, sp), __fmul_rn(2.0f, dot));
        float dd = __fsqrt_rn(fmaxf(d2, 0.0f));
        bool in = !(dd > RAD2);
        u64 m = __ballot(in);
        int cnt = __popcll(m);
        if (in){
            int slot = found + __popcll(m & ((1ull<<lane) - 1ull));
            if (slot < NSAMPLE) gout[slot] = i;
        }
        if (found == 0 && cnt > 0) first = base + (__ffsll(m) - 1);
        found += cnt;
        if (found >= NSAMPLE) break;
    }
    if (found < NSAMPLE){
        if (found == 0) first = cents[w];
        for (int slot = found + lane; slot < NSAMPLE; slot += 64) gout[slot] = first;
    }
}

// ---------------- conv1 (MFMA): 67->64; points-part via MFMA on pre-packed bf16,
// ---------------- xyz-norm (3ch) + bias in fp32 epilogue; fused stats ----------------
// grid 1024 blocks x 256; wave = 8 tiles of 16 rows; block = 512 rows.
__global__ __launch_bounds__(256) void conv1_kernel(const float* __restrict__ xyz, const u32* __restrict__ pbf,
                                                    const float* __restrict__ nxyz, const int* __restrict__ gidx,
                                                    const float* __restrict__ w, const float* __restrict__ bias,
                                                    u32* __restrict__ xout, float* __restrict__ stats)
{
    __shared__ float sxyz[512][3];
    const int tid = threadIdx.x;
    const int lane = tid & 63;
    const int wid = tid >> 6;
    const int quad = lane >> 4;
    const int col = lane & 15;
    const int blockbase = blockIdx.x*512;
    for (int r = tid; r < 512; r += 256){
        int m = blockbase + r;
        int b = m >> 15, s = (m >> 5) & 1023, g = gidx[m];
        const float* p3 = xyz + ((size_t)(b<<12) + g)*3;
        const float* c3 = nxyz + ((size_t)b*NPOINT + s)*3;
        sxyz[r][0] = p3[0]-c3[0]; sxyz[r][1] = p3[1]-c3[1]; sxyz[r][2] = p3[2]-c3[2];
    }
    // B-frags from points-channels (weight cols 3..66), xyz weights + bias per lane
    frag_ab Bf[4][2];
#pragma unroll
    for (int nt = 0; nt < 4; nt++)
#pragma unroll
        for (int kh = 0; kh < 2; kh++){
            const float* wr = w + (nt*16 + col)*67 + 3 + kh*32 + quad*8;
#pragma unroll
            for (int j = 0; j < 8; j++) Bf[nt][kh][j] = (short)f2bf(wr[j]);
        }
    float wx[4], wy[4], wz[4], biasl[4];
#pragma unroll
    for (int nt = 0; nt < 4; nt++){
        const float* wb = w + (nt*16 + col)*67;
        wx[nt] = wb[0]; wy[nt] = wb[1]; wz[nt] = wb[2];
        biasl[nt] = bias[nt*16 + col];
    }
    __syncthreads();
    float ssum[4] = {0,0,0,0}, ssq[4] = {0,0,0,0};
    u16* xo = (u16*)xout;
    const int tile0 = blockIdx.x*32 + wid*8;
#pragma unroll 2
    for (int t = 0; t < 8; t++){
        const int tile = tile0 + t;
        const size_t m0 = (size_t)tile * 16;
        const int b = (int)(m0 >> 15);
        const int g = gidx[m0 + col];
        const u32* arow = pbf + ((size_t)(b<<12) + g)*32;
        uint4 u0 = *(const uint4*)(arow + quad*4);
        uint4 u1 = *(const uint4*)(arow + 16 + quad*4);
        frag_ab Af0, Af1;
        __builtin_memcpy(&Af0, &u0, 16);
        __builtin_memcpy(&Af1, &u1, 16);
        frag_cd acc[4];
#pragma unroll
        for (int nt = 0; nt < 4; nt++){
            acc[nt] = (frag_cd){0.f, 0.f, 0.f, 0.f};
            acc[nt] = __builtin_amdgcn_mfma_f32_16x16x32_bf16(Af0, Bf[nt][0], acc[nt], 0, 0, 0);
            acc[nt] = __builtin_amdgcn_mfma_f32_16x16x32_bf16(Af1, Bf[nt][1], acc[nt], 0, 0, 0);
        }
        const int rbase = (int)(m0 - blockbase) + quad*4;
#pragma unroll
        for (int r = 0; r < 4; r++){
            float xnx = sxyz[rbase+r][0], xny = sxyz[rbase+r][1], xnz = sxyz[rbase+r][2];
#pragma unroll
            for (int nt = 0; nt < 4; nt++){
                float v = acc[nt][r] + biasl[nt];
                v = fmaf(wx[nt], xnx, v);
                v = fmaf(wy[nt], xny, v);
                v = fmaf(wz[nt], xnz, v);
                xo[(m0 + quad*4 + r)*64 + nt*16 + col] = f2bf(v);
                ssum[nt] += v;
                ssq[nt] = fmaf(v, v, ssq[nt]);
            }
        }
    }
#pragma unroll
    for (int nt = 0; nt < 4; nt++){
        ssum[nt] += __shfl_xor(ssum[nt], 16); ssq[nt] += __shfl_xor(ssq[nt], 16);
        ssum[nt] += __shfl_xor(ssum[nt], 32); ssq[nt] += __shfl_xor(ssq[nt], 32);
    }
    if (quad == 0){
        float* st = stats + (blockIdx.x & 7)*256;
#pragma unroll
        for (int nt = 0; nt < 4; nt++){
            atomicAdd(&st[nt*16 + col], ssum[nt]);
            atomicAdd(&st[128 + nt*16 + col], ssq[nt]);
        }
    }
}

// ---- in-block BN finalize: stats (8 replicas) + g/beta -> saff[a:0..127 | b:128..255] ----
__device__ inline void block_finalize(const float* __restrict__ stats, const float* __restrict__ g,
                                      const float* __restrict__ beta, float* saff, int C, int tid)
{
    if (tid < C){
        float sm = 0.f, sq = 0.f;
#pragma unroll
        for (int r = 0; r < 8; r++){ sm += stats[r*256+tid]; sq += stats[r*256+128+tid]; }
        const float invM = 1.0f / 524288.0f;
        float mu  = sm * invM;
        float var = fmaxf(sq * invM - mu*mu, 0.0f);
        float inv = 1.0f / sqrtf(var + 1e-5f);
        float a = g[tid] * inv;
        saff[tid] = a;
        saff[128+tid] = beta[tid] - mu*a;
    }
}

// ---- unpack 8 packed-bf16, apply affine+relu, emit bf16 frag half ----
__device__ inline void unpack_affine_relu(uint4 u, const float* ak, const float* bk, short* dst){
    const u32* uu = (const u32*)&u;
#pragma unroll
    for (int q = 0; q < 4; q++){
        u32 v = uu[q];
        float x0 = bf2f(v & 0xffffu);
        float x1 = bf2f(v >> 16);
        float f0 = fmaxf(fmaf(ak[2*q],   x0, bk[2*q]),   0.f);
        float f1 = fmaxf(fmaf(ak[2*q+1], x1, bk[2*q+1]), 0.f);
        dst[2*q]   = (short)f2bf(f0);
        dst[2*q+1] = (short)f2bf(f1);
    }
}

// ---------------- conv2 (MFMA): 64->64, in-block BN0 finalize, BN+relu on load, fused stats ----------------
__global__ __launch_bounds__(256) void conv2_kernel(const u32* __restrict__ xin, const float* __restrict__ stats_in,
                                                    const float* __restrict__ gw, const float* __restrict__ beta,
                                                    const float* __restrict__ w, const float* __restrict__ bias,
                                                    u32* __restrict__ xout, float* __restrict__ stats)
{
    __shared__ float saff[256];
    const int tid = threadIdx.x;
    block_finalize(stats_in, gw, beta, saff, 64, tid);
    const int lane = tid & 63;
    const int wid = tid >> 6;
    const int quad = lane >> 4;
    const int col = lane & 15;
    frag_ab Bf[4][2];
#pragma unroll
    for (int nt = 0; nt < 4; nt++)
#pragma unroll
        for (int kh = 0; kh < 2; kh++){
            const float* wr = w + (nt*16 + col)*64 + kh*32 + quad*8;
#pragma unroll
            for (int j = 0; j < 8; j++) Bf[nt][kh][j] = (short)f2bf(wr[j]);
        }
    float biasl[4];
#pragma unroll
    for (int nt = 0; nt < 4; nt++) biasl[nt] = bias[nt*16 + col];
    __syncthreads();
    float ak[2][8], bk[2][8];
#pragma unroll
    for (int kh = 0; kh < 2; kh++)
#pragma unroll
        for (int j = 0; j < 8; j++){
            int k = kh*32 + quad*8 + j;
            ak[kh][j] = saff[k]; bk[kh][j] = saff[128+k];
        }
    float ssum[4] = {0,0,0,0}, ssq[4] = {0,0,0,0};
    u16* xo = (u16*)xout;
    const int tile0 = blockIdx.x*64 + wid*16;
    for (int t = 0; t < 16; t++){
        const size_t m0 = (size_t)(tile0 + t) * 16;
        const u32* arow = xin + (m0 + col)*32;
        uint4 u0 = *(const uint4*)(arow + quad*4);
        uint4 u1 = *(const uint4*)(arow + 16 + quad*4);
        frag_ab Af0, Af1;
        unpack_affine_relu(u0, ak[0], bk[0], (short*)&Af0);
        unpack_affine_relu(u1, ak[1], bk[1], (short*)&Af1);
        frag_cd acc[4];
#pragma unroll
        for (int nt = 0; nt < 4; nt++){
            acc[nt] = (frag_cd){biasl[nt], biasl[nt], biasl[nt], biasl[nt]};
            acc[nt] = __builtin_amdgcn_mfma_f32_16x16x32_bf16(Af0, Bf[nt][0], acc[nt], 0, 0, 0);
            acc[nt] = __builtin_amdgcn_mfma_f32_16x16x32_bf16(Af1, Bf[nt][1], acc[nt], 0, 0, 0);
        }
#pragma unroll
        for (int nt = 0; nt < 4; nt++){
#pragma unroll
            for (int r = 0; r < 4; r++){
                float v = acc[nt][r];
                xo[(m0 + quad*4 + r)*64 + nt*16 + col] = f2bf(v);
                ssum[nt] += v;
                ssq[nt] = fmaf(v, v, ssq[nt]);
            }
        }
    }
#pragma unroll
    for (int nt = 0; nt < 4; nt++){
        ssum[nt] += __shfl_xor(ssum[nt], 16); ssq[nt] += __shfl_xor(ssq[nt], 16);
        ssum[nt] += __shfl_xor(ssum[nt], 32); ssq[nt] += __shfl_xor(ssq[nt], 32);
    }
    if (quad == 0){
        float* st = stats + (blockIdx.x & 7)*256;
#pragma unroll
        for (int nt = 0; nt < 4; nt++){
            atomicAdd(&st[nt*16 + col], ssum[nt]);
            atomicAdd(&st[128 + nt*16 + col], ssq[nt]);
        }
    }
}

// ---------------- conv3 (MFMA): 64->128, in-block BN1 finalize, fused stats + group max/min ----------------
__global__ __launch_bounds__(256) void conv3_kernel(const u32* __restrict__ xin, const float* __restrict__ stats_in,
                                                    const float* __restrict__ gw, const float* __restrict__ beta,
                                                    const float* __restrict__ w, const float* __restrict__ bias,
                                                    float* __restrict__ gmax, float* __restrict__ gmin,
                                                    float* __restrict__ stats)
{
    __shared__ float saff[256];
    const int tid = threadIdx.x;
    block_finalize(stats_in, gw, beta, saff, 64, tid);
    const int lane = tid & 63;
    const int wid = tid >> 6;
    const int quad = lane >> 4;
    const int col = lane & 15;
    frag_ab Bf[8][2];
#pragma unroll
    for (int nt = 0; nt < 8; nt++)
#pragma unroll
        for (int kh = 0; kh < 2; kh++){
            const float* wr = w + (nt*16 + col)*64 + kh*32 + quad*8;
#pragma unroll
            for (int j = 0; j < 8; j++) Bf[nt][kh][j] = (short)f2bf(wr[j]);
        }
    float biasl[8];
#pragma unroll
    for (int nt = 0; nt < 8; nt++) biasl[nt] = bias[nt*16 + col];
    __syncthreads();
    float ak[2][8], bk[2][8];
#pragma unroll
    for (int kh = 0; kh < 2; kh++)
#pragma unroll
        for (int j = 0; j < 8; j++){
            int k = kh*32 + quad*8 + j;
            ak[kh][j] = saff[k]; bk[kh][j] = saff[128+k];
        }
    float ssum[8], ssq[8], mx[8], mn[8];
#pragma unroll
    for (int nt = 0; nt < 8; nt++){ ssum[nt] = 0.f; ssq[nt] = 0.f; }
    const int tile0 = blockIdx.x*32 + wid*8;
#pragma unroll 2
    for (int t = 0; t < 8; t++){
        const size_t m0 = (size_t)(tile0 + t) * 16;
        const u32* arow = xin + (m0 + col)*32;
        uint4 u0 = *(const uint4*)(arow + quad*4);
        uint4 u1 = *(const uint4*)(arow + 16 + quad*4);
        frag_ab Af0, Af1;
        unpack_affine_relu(u0, ak[0], bk[0], (short*)&Af0);
        unpack_affine_relu(u1, ak[1], bk[1], (short*)&Af1);
        frag_cd acc[8];
#pragma unroll
        for (int nt = 0; nt < 8; nt++){
            acc[nt] = (frag_cd){biasl[nt], biasl[nt], biasl[nt], biasl[nt]};
            acc[nt] = __builtin_amdgcn_mfma_f32_16x16x32_bf16(Af0, Bf[nt][0], acc[nt], 0, 0, 0);
            acc[nt] = __builtin_amdgcn_mfma_f32_16x16x32_bf16(Af1, Bf[nt][1], acc[nt], 0, 0, 0);
        }
#pragma unroll
        for (int nt = 0; nt < 8; nt++){
            float a0 = fmaxf(fmaxf(acc[nt][0], acc[nt][1]), fmaxf(acc[nt][2], acc[nt][3]));
            float n0 = fminf(fminf(acc[nt][0], acc[nt][1]), fminf(acc[nt][2], acc[nt][3]));
            if ((t & 1) == 0){ mx[nt] = a0; mn[nt] = n0; }
            else { mx[nt] = fmaxf(mx[nt], a0); mn[nt] = fminf(mn[nt], n0); }
#pragma unroll
            for (int r = 0; r < 4; r++){
                float v = acc[nt][r];
                ssum[nt] += v;
                ssq[nt] = fmaf(v, v, ssq[nt]);
            }
        }
        if (t & 1){
#pragma unroll
            for (int nt = 0; nt < 8; nt++){
                mx[nt] = fmaxf(mx[nt], __shfl_xor(mx[nt], 16));
                mn[nt] = fminf(mn[nt], __shfl_xor(mn[nt], 16));
                mx[nt] = fmaxf(mx[nt], __shfl_xor(mx[nt], 32));
                mn[nt] = fminf(mn[nt], __shfl_xor(mn[nt], 32));
            }
            if (quad == 0){
                const int g = (tile0 + t - 1) >> 1;
#pragma unroll
                for (int nt = 0; nt < 8; nt++){
                    gmax[(size_t)g*128 + nt*16 + col] = mx[nt];
                    gmin[(size_t)g*128 + nt*16 + col] = mn[nt];
                }
            }
        }
    }
#pragma unroll
    for (int nt = 0; nt < 8; nt++){
        ssum[nt] += __shfl_xor(ssum[nt], 16); ssq[nt] += __shfl_xor(ssq[nt], 16);
        ssum[nt] += __shfl_xor(ssum[nt], 32); ssq[nt] += __shfl_xor(ssq[nt], 32);
    }
    if (quad == 0){
        float* st = stats + (blockIdx.x & 7)*256;
#pragma unroll
        for (int nt = 0; nt < 8; nt++){
            atomicAdd(&st[nt*16 + col], ssum[nt]);
            atomicAdd(&st[128 + nt*16 + col], ssq[nt]);
        }
    }
}

// ---------------- pool: in-block BN2 finalize + relu from group max/min ----------------
// grid 1024 blocks x 256; each thread 8 elements.
__global__ __launch_bounds__(256) void pool_kernel(const float* __restrict__ gmax, const float* __restrict__ gmin,
                                                   const float* __restrict__ stats_in, const float* __restrict__ gw,
                                                   const float* __restrict__ beta, float* __restrict__ out)
{
    __shared__ float saff[256];
    const int tid = threadIdx.x;
    block_finalize(stats_in, gw, beta, saff, 128, tid);
    __syncthreads();
    const int base = blockIdx.x*2048 + tid;
#pragma unroll
    for (int k = 0; k < 8; k++){
        int idx = base + k*256;
        int o = idx & 127;
        float a = saff[o], bsh = saff[128+o];
        float v = (a >= 0.f) ? fmaf(a, gmax[idx], bsh) : fmaf(a, gmin[idx], bsh);
        out[(size_t)BB*NPOINT*3 + idx] = fmaxf(v, 0.f);
    }
}

extern "C" void kernel_launch(void* const* d_in, const int* in_sizes, int n_in,
                              void* d_out, int out_size, void* d_ws, size_t ws_size,
                              hipStream_t stream)
{
    const float* xyz    = (const float*)d_in[0];
    const float* points = (const float*)d_in[1];
    const float* w0  = (const float*)d_in[2];
    const float* b0  = (const float*)d_in[3];
    const float* g0  = (const float*)d_in[4];
    const float* be0 = (const float*)d_in[5];
    const float* w1  = (const float*)d_in[6];
    const float* b1  = (const float*)d_in[7];
    const float* g1  = (const float*)d_in[8];
    const float* be1 = (const float*)d_in[9];
    const float* w2  = (const float*)d_in[10];
    const float* b2  = (const float*)d_in[11];
    const float* g2  = (const float*)d_in[12];
    const float* be2 = (const float*)d_in[13];
    float* out = (float*)d_out;
    char* ws = (char*)d_ws;

    int*   cents = (int*)(ws + 0);                 //  64 KiB
    float* nxyz  = (float*)(ws + 65536);           // 192 KiB
    int*   gidx  = (int*)(ws + 262144);            //   2 MiB -> ends 2359296
    float* stats = (float*)(ws + 2359296);         //  24 KiB (3 layers x 8 replicas x 256 f)
    u32*   x1buf = (u32*)(ws + 2386944);           //  64 MiB (conv1 out bf16)
    u32*   x2buf = (u32*)(ws + 69495808);          //  64 MiB (conv2 out bf16)
    float* gmax  = (float*)(ws + 136604672);       // 8.4 MiB (conv3 out; aliases pbf - dead by then)
    float* gmin  = (float*)(ws + 144993280);       // 8.4 MiB
    u32*   pbf   = (u32*)(ws + 136604672);         // 8.4 MiB packed bf16 points (dead after conv1)

    hipMemsetAsync(stats, 0, 6144*sizeof(float), stream);
    fps_kernel<<<16, 256, 0, stream>>>(xyz, cents);
    gather_newxyz_kernel<<<192, 256, 0, stream>>>(xyz, cents, out, nxyz);
    pack_points_kernel<<<8192, 256, 0, stream>>>(points, pbf);
    ballquery_kernel<<<4096, 256, 0, stream>>>(xyz, nxyz, cents, gidx);
    conv1_kernel<<<1024, 256, 0, stream>>>(xyz, pbf, nxyz, gidx, w0, b0, x1buf, stats);
    conv2_kernel<<<512, 256, 0, stream>>>(x1buf, stats, g0, be0, w1, b1, x2buf, stats + 2048);
    conv3_kernel<<<1024, 256, 0, stream>>>(x2buf, stats + 2048, g1, be1, w2, b2, gmax, gmin, stats + 4096);
    pool_kernel<<<1024, 256, 0, stream>>>(gmax, gmin, stats + 4096, g2, be2, out);
}